// Round 1
// baseline (2785.857 us; speedup 1.0000x reference)
//
#include <hip/hip_runtime.h>
#include <math.h>

#define Bb   64
#define Nn   256
#define Mm   16
#define ONF  92
#define OEF  41
#define NF   128
#define EF   64
#define KDIM 320   // 2*NF + EF
#define ODIM 256   // 2*NF
#define FINAL 128

__device__ __forceinline__ float sigmoidf_(float x) { return 1.0f / (1.0f + expf(-x)); }
__device__ __forceinline__ float softplusf_(float x) {
    // stable log(1+exp(x))
    return fmaxf(x, 0.0f) + log1pf(expf(-fabsf(x)));
}

// ---------- tiny prep kernels ----------
// in: [O][I] -> out: [I][O]
__global__ void k_transpose(const float* __restrict__ in, float* __restrict__ out, int O, int I)
{
    int t = blockIdx.x * 256 + threadIdx.x;
    if (t < O * I) {
        int o = t / I, i = t - o * I;
        out[i * O + o] = in[t];
    }
}

// in: [ODIM][KDIM] -> out: [KDIM/4][ODIM][4]  (per-thread float4 weight loads)
__global__ void k_transpose_c4(const float* __restrict__ in, float* __restrict__ out)
{
    int t = blockIdx.x * 256 + threadIdx.x;
    if (t < ODIM * KDIM) {
        int o = t / KDIM, i = t - o * KDIM;
        out[(i >> 2) * (ODIM * 4) + o * 4 + (i & 3)] = in[t];
    }
}

__global__ void k_da(const float* __restrict__ dis, const float* __restrict__ pw,
                     const float* __restrict__ pb, float* __restrict__ DA)
{
    int t = blockIdx.x * 256 + threadIdx.x;
    if (t < Nn * Nn) DA[t] = sigmoidf_(fmaf(*pw, dis[t], *pb));
}

// ---------- node embed: nf0 = node_fea @ Wn^T + bn ----------
__global__ __launch_bounds__(128) void k_embed_node(
    const float* __restrict__ x, const float* __restrict__ WnT,
    const float* __restrict__ bn, float* __restrict__ out)
{
    int node = blockIdx.x;         // b*Nn + n
    int o = threadIdx.x;           // 0..127
    __shared__ float xs[ONF];
    if (o < ONF) xs[o] = x[node * ONF + o];
    __syncthreads();
    float a = bn[o];
    #pragma unroll
    for (int i = 0; i < ONF; i++) a = fmaf(xs[i], WnT[i * NF + o], a);
    out[node * NF + o] = a;
}

// ---------- conv layer ----------
__global__ __launch_bounds__(256) void k_conv(
    const float* __restrict__ nf_in,     // [B*N, NF]
    const float* __restrict__ edge_fea,  // [B*N, M*OEF]
    const int*   __restrict__ eidx,      // [B*N, M]
    const float* __restrict__ WeT,       // [OEF][EF]
    const float* __restrict__ be,        // [EF]
    const float* __restrict__ WTC,       // [KDIM/4][ODIM][4]
    const float* __restrict__ bias,      // [ODIM]
    const float* __restrict__ palpha,
    float*       __restrict__ nf_out)    // [B*N, NF]
{
    int node = blockIdx.x;     // b*Nn + n
    int b = node >> 8;         // Nn = 256
    int o = threadIdx.x;       // 0..255 : output column

    __shared__ __align__(16) float total[Mm][KDIM];   // 20480 B
    __shared__ float core_s[Mm][NF];                  //  8192 B
    __shared__ float e_s[Mm * OEF];                   //  2624 B
    __shared__ int   idx_s[Mm];

    if (o < Mm) idx_s[o] = eidx[node * Mm + o];
    for (int k = o; k < Mm * OEF; k += 256) e_s[k] = edge_fea[node * (Mm * OEF) + k];
    __syncthreads();

    // fill total = [self | gathered | edge-embed]
    const float* selfrow = nf_in + node * NF;
    for (int k = o; k < Mm * NF; k += 256) {
        int m = k >> 7, f = k & 127;
        total[m][f] = selfrow[f];
        int j = idx_s[m]; j = j < 0 ? 0 : j;
        total[m][NF + f] = nf_in[(b * Nn + j) * NF + f];
    }
    for (int k = o; k < Mm * EF; k += 256) {
        int m = k >> 6, f = k & 63;
        float a = be[f];
        const float* er = &e_s[m * OEF];
        #pragma unroll
        for (int i = 0; i < OEF; i++) a = fmaf(er[i], WeT[i * EF + f], a);
        total[m][2 * NF + f] = a;
    }
    __syncthreads();

    // gated[m][o] = total[m][:] . W[o][:] + bias[o]
    float acc[Mm];
    float bo = bias[o];
    #pragma unroll
    for (int m = 0; m < Mm; m++) acc[m] = bo;

    const float4* W4 = (const float4*)WTC;
    for (int i4 = 0; i4 < KDIM / 4; i4++) {
        float4 w = W4[i4 * ODIM + o];
        #pragma unroll
        for (int m = 0; m < Mm; m++) {
            float4 t = *(const float4*)&total[m][i4 * 4];
            acc[m] = fmaf(t.x, w.x, acc[m]);
            acc[m] = fmaf(t.y, w.y, acc[m]);
            acc[m] = fmaf(t.z, w.z, acc[m]);
            acc[m] = fmaf(t.w, w.w, acc[m]);
        }
    }

    // split: o<128 -> filter, o>=128 -> core
    if (o >= NF) {
        #pragma unroll
        for (int m = 0; m < Mm; m++) core_s[m][o - NF] = softplusf_(acc[m]);
    }
    __syncthreads();
    if (o < NF) {
        float s = 0.0f;
        #pragma unroll
        for (int m = 0; m < Mm; m++) {
            if (idx_s[m] >= 0) s += sigmoidf_(acc[m]) * core_s[m][o];
        }
        float alpha = *palpha;
        nf_out[node * NF + o] = softplusf_(fmaf(alpha, selfrow[o], s));
    }
}

// ---------- final linear: out[:, :, 0:64] = nf3 @ Wf^T + bf ----------
__global__ __launch_bounds__(256) void k_final(
    const float* __restrict__ nf, const float* __restrict__ WfT,
    const float* __restrict__ bfv, float* __restrict__ out)
{
    int node4 = blockIdx.x * 4;
    int e = threadIdx.x >> 6, f = threadIdx.x & 63;
    __shared__ float xs[4 * NF];
    for (int k = threadIdx.x; k < 4 * NF; k += 256) xs[k] = nf[node4 * NF + k];
    __syncthreads();
    float a = bfv[f];
    const float* xr = &xs[e * NF];
    #pragma unroll
    for (int i = 0; i < NF; i++) a = fmaf(xr[i], WfT[i * (FINAL / 2) + f], a);
    out[(node4 + e) * FINAL + f] = a;
}

// ---------- node1: out[:, :, 64:128] = DA @ out[:, :, 0:64] (per batch) ----------
__global__ __launch_bounds__(256) void k_node1(
    const float* __restrict__ DA, float* __restrict__ out)
{
    int pair = blockIdx.x * 4 + (threadIdx.x >> 6);  // b*Nn + i
    int f = threadIdx.x & 63;
    int b = pair >> 8, i = pair & 255;
    const float* DArow = DA + i * Nn;
    const float* obase = out + (size_t)b * Nn * FINAL;
    float acc = 0.0f;
    for (int j = 0; j < Nn; j++) acc = fmaf(DArow[j], obase[j * FINAL + f], acc);
    out[(size_t)pair * FINAL + (FINAL / 2) + f] = acc;
}

extern "C" void kernel_launch(void* const* d_in, const int* in_sizes, int n_in,
                              void* d_out, int out_size, void* d_ws, size_t ws_size,
                              hipStream_t stream)
{
    const float* node_fea = (const float*)d_in[0];
    const float* edge_fea = (const float*)d_in[1];
    const int*   eidx     = (const int*)  d_in[2];
    const float* dis      = (const float*)d_in[3];
    const float* Wn = (const float*)d_in[4];
    const float* bn = (const float*)d_in[5];
    const float* We = (const float*)d_in[6];
    const float* be = (const float*)d_in[7];
    const float* W1 = (const float*)d_in[8];
    const float* b1 = (const float*)d_in[9];
    const float* a1 = (const float*)d_in[10];
    const float* W2 = (const float*)d_in[11];
    const float* b2 = (const float*)d_in[12];
    const float* a2 = (const float*)d_in[13];
    const float* W3 = (const float*)d_in[14];
    const float* b3 = (const float*)d_in[15];
    const float* a3 = (const float*)d_in[16];
    const float* Wf = (const float*)d_in[17];
    const float* bf = (const float*)d_in[18];
    const float* DAw = (const float*)d_in[19];
    const float* DAb = (const float*)d_in[20];
    float* out = (float*)d_out;

    // workspace layout (floats): ~18.1 MB total
    float* ws   = (float*)d_ws;
    float* nfA  = ws;                     // B*N*NF = 2097152
    float* nfB  = nfA + Bb * Nn * NF;     // 2097152
    float* DAbuf= nfB + Bb * Nn * NF;     // 65536
    float* WTC1 = DAbuf + Nn * Nn;        // 81920
    float* WTC2 = WTC1 + ODIM * KDIM;
    float* WTC3 = WTC2 + ODIM * KDIM;
    float* WnT  = WTC3 + ODIM * KDIM;     // 11776
    float* WeT  = WnT + ONF * NF;         // 2624
    float* WfT  = WeT + OEF * EF;         // 8192

    // prep
    hipLaunchKernelGGL(k_transpose, dim3((NF * ONF + 255) / 256), dim3(256), 0, stream,
                       Wn, WnT, NF, ONF);
    hipLaunchKernelGGL(k_transpose, dim3((EF * OEF + 255) / 256), dim3(256), 0, stream,
                       We, WeT, EF, OEF);
    hipLaunchKernelGGL(k_transpose, dim3(((FINAL / 2) * NF + 255) / 256), dim3(256), 0, stream,
                       Wf, WfT, FINAL / 2, NF);
    hipLaunchKernelGGL(k_transpose_c4, dim3((ODIM * KDIM + 255) / 256), dim3(256), 0, stream, W1, WTC1);
    hipLaunchKernelGGL(k_transpose_c4, dim3((ODIM * KDIM + 255) / 256), dim3(256), 0, stream, W2, WTC2);
    hipLaunchKernelGGL(k_transpose_c4, dim3((ODIM * KDIM + 255) / 256), dim3(256), 0, stream, W3, WTC3);
    hipLaunchKernelGGL(k_da, dim3((Nn * Nn + 255) / 256), dim3(256), 0, stream, dis, DAw, DAb, DAbuf);

    // embeds
    hipLaunchKernelGGL(k_embed_node, dim3(Bb * Nn), dim3(128), 0, stream, node_fea, WnT, bn, nfA);

    // conv x3 (ping-pong nfA/nfB)
    hipLaunchKernelGGL(k_conv, dim3(Bb * Nn), dim3(256), 0, stream,
                       nfA, edge_fea, eidx, WeT, be, WTC1, b1, a1, nfB);
    hipLaunchKernelGGL(k_conv, dim3(Bb * Nn), dim3(256), 0, stream,
                       nfB, edge_fea, eidx, WeT, be, WTC2, b2, a2, nfA);
    hipLaunchKernelGGL(k_conv, dim3(Bb * Nn), dim3(256), 0, stream,
                       nfA, edge_fea, eidx, WeT, be, WTC3, b3, a3, nfB);

    // final linear -> out[:, :, 0:64], then node1 -> out[:, :, 64:128]
    hipLaunchKernelGGL(k_final, dim3(Bb * Nn / 4), dim3(256), 0, stream, nfB, WfT, bf, out);
    hipLaunchKernelGGL(k_node1, dim3(Bb * Nn / 4), dim3(256), 0, stream, DAbuf, out);
}

// Round 2
// 903.129 us; speedup vs baseline: 3.0847x; 3.0847x over previous
//
#include <hip/hip_runtime.h>
#include <hip/hip_bf16.h>
#include <math.h>

#define Bb   64
#define Nn   256
#define Mm   16
#define ONF  92
#define OEF  41
#define NF   128
#define EF   64
#define KDIM 320   // 2*NF + EF
#define ODIM 256   // 2*NF
#define FINAL 128

typedef __attribute__((ext_vector_type(8))) short short8;
typedef __attribute__((ext_vector_type(4))) float f32x4;

__device__ __forceinline__ float sigmoidf_(float x) { return 1.0f / (1.0f + expf(-x)); }
__device__ __forceinline__ float softplusf_(float x) {
    return fmaxf(x, 0.0f) + log1pf(expf(-fabsf(x)));
}
__device__ __forceinline__ __hip_bfloat16 to_bf16(float x) { return __float2bfloat16(x); }

// ---------- tiny prep kernels ----------
// in: [O][I] -> out: [I][O]  (f32)
__global__ void k_transpose(const float* __restrict__ in, float* __restrict__ out, int O, int I)
{
    int t = blockIdx.x * 256 + threadIdx.x;
    if (t < O * I) {
        int o = t / I, i = t - o * I;
        out[i * O + o] = in[t];
    }
}

// f32 -> bf16 elementwise (same layout)
__global__ void k_w2bf(const float* __restrict__ in, __hip_bfloat16* __restrict__ out, int n)
{
    int t = blockIdx.x * 256 + threadIdx.x;
    if (t < n) out[t] = to_bf16(in[t]);
}

__global__ void k_da(const float* __restrict__ dis, const float* __restrict__ pw,
                     const float* __restrict__ pb, float* __restrict__ DA)
{
    int t = blockIdx.x * 256 + threadIdx.x;
    if (t < Nn * Nn) DA[t] = sigmoidf_(fmaf(*pw, dis[t], *pb));
}

// ---------- edge embed (once): ef_bf[row][col] = edge_fea[row][:41] . WeT[:,col] + be[col]
__global__ __launch_bounds__(256) void k_ef(
    const float* __restrict__ edge_fea, const float* __restrict__ WeT,
    const float* __restrict__ be, __hip_bfloat16* __restrict__ ef_bf)
{
    int id = blockIdx.x * 256 + threadIdx.x;   // < B*N*M*EF
    int row = id >> 6, col = id & 63;
    const float* er = edge_fea + (size_t)row * OEF;
    float a = be[col];
    #pragma unroll
    for (int i = 0; i < OEF; i++) a = fmaf(er[i], WeT[i * EF + col], a);
    ef_bf[id] = to_bf16(a);
}

// ---------- node embed: nf0 = node_fea @ Wn^T + bn (bf16 out) ----------
__global__ __launch_bounds__(128) void k_embed_node(
    const float* __restrict__ x, const float* __restrict__ WnT,
    const float* __restrict__ bn, __hip_bfloat16* __restrict__ out)
{
    int node = blockIdx.x;
    int o = threadIdx.x;
    __shared__ float xs[ONF];
    if (o < ONF) xs[o] = x[node * ONF + o];
    __syncthreads();
    float a = bn[o];
    #pragma unroll
    for (int i = 0; i < ONF; i++) a = fmaf(xs[i], WnT[i * NF + o], a);
    out[node * NF + o] = to_bf16(a);
}

// ---------- conv layer: MFMA ----------
// 4 nodes/block, A-tile 64x320 bf16 in LDS, B from global bf16 W [256][320].
// Wave w owns filter cols [32w,32w+32) and core cols [128+32w, 128+32w+32):
// same lane/reg pairing -> in-register gating epilogue.
template<bool PRECOMP>
__global__ __launch_bounds__(256) void k_conv_mfma(
    const __hip_bfloat16* __restrict__ nf_in,   // [B*N][NF] bf16
    const float* __restrict__ edge_fea,         // [B*N*M][OEF] f32  (PRECOMP=false)
    const __hip_bfloat16* __restrict__ ef_bf,   // [B*N*M][EF] bf16  (PRECOMP=true)
    const int*   __restrict__ eidx,             // [B*N][M]
    const float* __restrict__ WeT,              // [OEF][EF] f32     (PRECOMP=false)
    const float* __restrict__ be,               // [EF]              (PRECOMP=false)
    const __hip_bfloat16* __restrict__ Wb,      // [ODIM][KDIM] bf16
    const float* __restrict__ bias,             // [ODIM]
    const float* __restrict__ palpha,
    __hip_bfloat16* __restrict__ nf_out)        // [B*N][NF] bf16
{
    constexpr int LDA = 328;                    // bf16 elems; 656B row = 164 dwords -> 2-way (free)
    __shared__ __hip_bfloat16 A_s[64 * LDA];    // 41984 B
    __shared__ int idx_s[64];
    __shared__ float e_s[PRECOMP ? 1 : 64 * OEF];
    __shared__ float W_s[PRECOMP ? 1 : OEF * EF];

    const int node0 = blockIdx.x * 4;
    const int b = node0 >> 8;
    const int t = threadIdx.x;

    if (t < 64) idx_s[t] = eidx[node0 * Mm + t];
    if (!PRECOMP) {
        for (int c = t; c < 64 * OEF; c += 256) e_s[c] = edge_fea[(size_t)(node0 * Mm) * OEF + c];
        for (int c = t; c < OEF * EF; c += 256) W_s[c] = WeT[c];
    }
    __syncthreads();

    // stage self (k 0..127) + gathered (k 128..255): 2048 chunks of 16B
    for (int c = t; c < 2048; c += 256) {
        int part = c >> 10;          // 0 self, 1 gathered
        int rem  = c & 1023;
        int row  = rem >> 4;         // 0..63
        int off  = (rem & 15) << 3;  // 0..120 step 8 (bf16 elems)
        int src_node;
        if (part == 0) src_node = node0 + (row >> 4);
        else { int j = idx_s[row]; j = j < 0 ? 0 : j; src_node = (b << 8) + j; }
        *(uint4*)(A_s + row * LDA + part * NF + off) =
            *(const uint4*)(nf_in + src_node * NF + off);
    }
    // stage edge-embed (k 256..319)
    if (PRECOMP) {
        for (int c = t; c < 512; c += 256) {
            int row = c >> 3, off = (c & 7) << 3;
            *(uint4*)(A_s + row * LDA + 2 * NF + off) =
                *(const uint4*)(ef_bf + (size_t)(node0 * Mm + row) * EF + off);
        }
    } else {
        for (int c = t; c < 64 * EF; c += 256) {
            int row = c >> 6, col = c & 63;
            float a = be[col];
            #pragma unroll
            for (int i = 0; i < OEF; i++) a = fmaf(e_s[row * OEF + i], W_s[i * EF + col], a);
            A_s[row * LDA + 2 * NF + col] = to_bf16(a);
        }
    }
    __syncthreads();

    const int wv = t >> 6, lane = t & 63;
    const int q = lane >> 4, ln16 = lane & 15;

    // acc[mt][p]: mt = node (M-tile), p = tile pair index
    f32x4 accF[4][2], accC[4][2];
    #pragma unroll
    for (int p = 0; p < 2; p++) {
        int colF = (2 * wv + p) * 16 + ln16;
        float bF = bias[colF], bC = bias[colF + NF];
        #pragma unroll
        for (int mt = 0; mt < 4; mt++) {
            accF[mt][p] = (f32x4){bF, bF, bF, bF};
            accC[mt][p] = (f32x4){bC, bC, bC, bC};
        }
    }

    for (int k0 = 0; k0 < KDIM; k0 += 32) {
        short8 af[4];
        #pragma unroll
        for (int mt = 0; mt < 4; mt++)
            af[mt] = *(const short8*)(A_s + (16 * mt + ln16) * LDA + k0 + q * 8);
        short8 bF[2], bC[2];
        #pragma unroll
        for (int p = 0; p < 2; p++) {
            int nF = (2 * wv + p) * 16 + ln16;
            bF[p] = *(const short8*)(Wb + (size_t)nF * KDIM + k0 + q * 8);
            bC[p] = *(const short8*)(Wb + (size_t)(nF + NF) * KDIM + k0 + q * 8);
        }
        #pragma unroll
        for (int mt = 0; mt < 4; mt++)
            #pragma unroll
            for (int p = 0; p < 2; p++) {
                accF[mt][p] = __builtin_amdgcn_mfma_f32_16x16x32_bf16(af[mt], bF[p], accF[mt][p], 0, 0, 0);
                accC[mt][p] = __builtin_amdgcn_mfma_f32_16x16x32_bf16(af[mt], bC[p], accC[mt][p], 0, 0, 0);
            }
    }

    // epilogue: filter = sigmoid(gF)*mask, core = softplus(gC); sum over m; softplus(alpha*self + sum)
    const float alpha = *palpha;
    #pragma unroll
    for (int mt = 0; mt < 4; mt++) {
        const int gnode = node0 + mt;
        #pragma unroll
        for (int p = 0; p < 2; p++) {
            float partial = 0.0f;
            #pragma unroll
            for (int r = 0; r < 4; r++) {
                int m = q * 4 + r;
                bool msk = idx_s[mt * 16 + m] >= 0;
                float f = sigmoidf_(accF[mt][p][r]);
                float c = softplusf_(accC[mt][p][r]);
                partial += msk ? f * c : 0.0f;
            }
            partial += __shfl_xor(partial, 16);
            partial += __shfl_xor(partial, 32);
            if (q == 0) {
                int col = (2 * wv + p) * 16 + ln16;
                float self = __bfloat162float(nf_in[gnode * NF + col]);
                nf_out[gnode * NF + col] = to_bf16(softplusf_(fmaf(alpha, self, partial)));
            }
        }
    }
}

// ---------- final linear: out[:, :, 0:64] = nf3 @ Wf^T + bf (f32 out) ----------
__global__ __launch_bounds__(256) void k_final(
    const __hip_bfloat16* __restrict__ nf, const float* __restrict__ WfT,
    const float* __restrict__ bfv, float* __restrict__ out)
{
    int node4 = blockIdx.x * 4;
    int e = threadIdx.x >> 6, f = threadIdx.x & 63;
    __shared__ float xs[4 * NF];
    for (int k = threadIdx.x; k < 4 * NF; k += 256) xs[k] = __bfloat162float(nf[node4 * NF + k]);
    __syncthreads();
    float a = bfv[f];
    const float* xr = &xs[e * NF];
    #pragma unroll
    for (int i = 0; i < NF; i++) a = fmaf(xr[i], WfT[i * (FINAL / 2) + f], a);
    out[(node4 + e) * FINAL + f] = a;
}

// ---------- node1: out[:, :, 64:128] = DA @ out[:, :, 0:64] (per batch) ----------
__global__ __launch_bounds__(256) void k_node1(
    const float* __restrict__ DA, float* __restrict__ out)
{
    int pair = blockIdx.x * 4 + (threadIdx.x >> 6);  // b*Nn + i
    int f = threadIdx.x & 63;
    int b = pair >> 8, i = pair & 255;
    const float* DArow = DA + i * Nn;
    const float* obase = out + (size_t)b * Nn * FINAL;
    float acc = 0.0f;
    for (int j = 0; j < Nn; j++) acc = fmaf(DArow[j], obase[j * FINAL + f], acc);
    out[(size_t)pair * FINAL + (FINAL / 2) + f] = acc;
}

extern "C" void kernel_launch(void* const* d_in, const int* in_sizes, int n_in,
                              void* d_out, int out_size, void* d_ws, size_t ws_size,
                              hipStream_t stream)
{
    const float* node_fea = (const float*)d_in[0];
    const float* edge_fea = (const float*)d_in[1];
    const int*   eidx     = (const int*)  d_in[2];
    const float* dis      = (const float*)d_in[3];
    const float* Wn = (const float*)d_in[4];
    const float* bn = (const float*)d_in[5];
    const float* We = (const float*)d_in[6];
    const float* be = (const float*)d_in[7];
    const float* W1 = (const float*)d_in[8];
    const float* b1 = (const float*)d_in[9];
    const float* a1 = (const float*)d_in[10];
    const float* W2 = (const float*)d_in[11];
    const float* b2 = (const float*)d_in[12];
    const float* a2 = (const float*)d_in[13];
    const float* W3 = (const float*)d_in[14];
    const float* b3 = (const float*)d_in[15];
    const float* a3 = (const float*)d_in[16];
    const float* Wf = (const float*)d_in[17];
    const float* bf = (const float*)d_in[18];
    const float* DAw = (const float*)d_in[19];
    const float* DAb = (const float*)d_in[20];
    float* out = (float*)d_out;

    // workspace layout (bytes, 256-aligned blocks)
    char* base = (char*)d_ws;
    size_t off = 0;
    auto alloc = [&](size_t bytes) { char* p = base + off; off = (off + bytes + 255) & ~(size_t)255; return p; };
    __hip_bfloat16* nfA = (__hip_bfloat16*)alloc((size_t)Bb * Nn * NF * 2);
    __hip_bfloat16* nfB = (__hip_bfloat16*)alloc((size_t)Bb * Nn * NF * 2);
    __hip_bfloat16* W1b = (__hip_bfloat16*)alloc((size_t)ODIM * KDIM * 2);
    __hip_bfloat16* W2b = (__hip_bfloat16*)alloc((size_t)ODIM * KDIM * 2);
    __hip_bfloat16* W3b = (__hip_bfloat16*)alloc((size_t)ODIM * KDIM * 2);
    float* WnT   = (float*)alloc((size_t)ONF * NF * 4);
    float* WeT   = (float*)alloc((size_t)OEF * EF * 4);
    float* WfT   = (float*)alloc((size_t)NF * (FINAL / 2) * 4);
    float* DAbuf = (float*)alloc((size_t)Nn * Nn * 4);
    size_t fixed_bytes = off;
    __hip_bfloat16* efb = (__hip_bfloat16*)alloc((size_t)Bb * Nn * Mm * EF * 2);  // 33.5 MB
    const bool precomp = (ws_size >= off);   // use ef precompute only if ws fits it
    (void)fixed_bytes;

    // prep
    hipLaunchKernelGGL(k_transpose, dim3((NF * ONF + 255) / 256), dim3(256), 0, stream, Wn, WnT, NF, ONF);
    hipLaunchKernelGGL(k_transpose, dim3((EF * OEF + 255) / 256), dim3(256), 0, stream, We, WeT, EF, OEF);
    hipLaunchKernelGGL(k_transpose, dim3(((FINAL / 2) * NF + 255) / 256), dim3(256), 0, stream, Wf, WfT, FINAL / 2, NF);
    hipLaunchKernelGGL(k_w2bf, dim3((ODIM * KDIM + 255) / 256), dim3(256), 0, stream, W1, W1b, ODIM * KDIM);
    hipLaunchKernelGGL(k_w2bf, dim3((ODIM * KDIM + 255) / 256), dim3(256), 0, stream, W2, W2b, ODIM * KDIM);
    hipLaunchKernelGGL(k_w2bf, dim3((ODIM * KDIM + 255) / 256), dim3(256), 0, stream, W3, W3b, ODIM * KDIM);
    hipLaunchKernelGGL(k_da, dim3((Nn * Nn + 255) / 256), dim3(256), 0, stream, dis, DAw, DAb, DAbuf);

    if (precomp)
        hipLaunchKernelGGL(k_ef, dim3(Bb * Nn * Mm * EF / 256), dim3(256), 0, stream, edge_fea, WeT, be, efb);

    hipLaunchKernelGGL(k_embed_node, dim3(Bb * Nn), dim3(128), 0, stream, node_fea, WnT, bn, nfA);

    if (precomp) {
        hipLaunchKernelGGL((k_conv_mfma<true>), dim3(Bb * Nn / 4), dim3(256), 0, stream,
                           nfA, edge_fea, efb, eidx, WeT, be, W1b, b1, a1, nfB);
        hipLaunchKernelGGL((k_conv_mfma<true>), dim3(Bb * Nn / 4), dim3(256), 0, stream,
                           nfB, edge_fea, efb, eidx, WeT, be, W2b, b2, a2, nfA);
        hipLaunchKernelGGL((k_conv_mfma<true>), dim3(Bb * Nn / 4), dim3(256), 0, stream,
                           nfA, edge_fea, efb, eidx, WeT, be, W3b, b3, a3, nfB);
    } else {
        hipLaunchKernelGGL((k_conv_mfma<false>), dim3(Bb * Nn / 4), dim3(256), 0, stream,
                           nfA, edge_fea, efb, eidx, WeT, be, W1b, b1, a1, nfB);
        hipLaunchKernelGGL((k_conv_mfma<false>), dim3(Bb * Nn / 4), dim3(256), 0, stream,
                           nfB, edge_fea, efb, eidx, WeT, be, W2b, b2, a2, nfA);
        hipLaunchKernelGGL((k_conv_mfma<false>), dim3(Bb * Nn / 4), dim3(256), 0, stream,
                           nfA, edge_fea, efb, eidx, WeT, be, W3b, b3, a3, nfB);
    }

    hipLaunchKernelGGL(k_final, dim3(Bb * Nn / 4), dim3(256), 0, stream, nfB, WfT, bf, out);
    hipLaunchKernelGGL(k_node1, dim3(Bb * Nn / 4), dim3(256), 0, stream, DAbuf, out);
}

// Round 3
// 521.691 us; speedup vs baseline: 5.3401x; 1.7312x over previous
//
#include <hip/hip_runtime.h>
#include <hip/hip_bf16.h>
#include <math.h>

#define Bb   64
#define Nn   256
#define Mm   16
#define ONF  92
#define OEF  41
#define NF   128
#define EF   64
#define KDIM 320   // 2*NF + EF
#define ODIM 256   // 2*NF
#define FINAL 128

typedef __attribute__((ext_vector_type(8))) short short8;
typedef __attribute__((ext_vector_type(4))) float f32x4;

__device__ __forceinline__ float sigmoidf_(float x) {
    float e = __expf(-x);
    return __builtin_amdgcn_rcpf(1.0f + e);
}
__device__ __forceinline__ float softplusf_(float x) {
    return fmaxf(x, 0.0f) + __logf(1.0f + __expf(-fabsf(x)));
}
__device__ __forceinline__ __hip_bfloat16 to_bf16(float x) { return __float2bfloat16(x); }

// ---------- tiny prep kernels ----------
// in: [O][I] -> out: [I][O]  (f32)
__global__ void k_transpose(const float* __restrict__ in, float* __restrict__ out, int O, int I)
{
    int t = blockIdx.x * 256 + threadIdx.x;
    if (t < O * I) {
        int o = t / I, i = t - o * I;
        out[i * O + o] = in[t];
    }
}

// W [ODIM][KDIM] f32 -> bf16 in MFMA-B-fragment order:
// dst elem = ((tile*10 + k0)*64 + q*16 + ln16)*8 + j
//   where n = tile*16+ln16, k = k0*32 + q*8 + j
__global__ void k_wswz(const float* __restrict__ in, __hip_bfloat16* __restrict__ out)
{
    int t = blockIdx.x * 256 + threadIdx.x;
    if (t < ODIM * KDIM) {
        int n = t / KDIM, k = t - n * KDIM;
        int tile = n >> 4, ln16 = n & 15;
        int k0 = k >> 5, q = (k >> 3) & 3, j = k & 7;
        out[(size_t)(((tile * 10 + k0) << 6) + (q << 4) + ln16) * 8 + j] = to_bf16(in[t]);
    }
}

__global__ void k_da(const float* __restrict__ dis, const float* __restrict__ pw,
                     const float* __restrict__ pb, float* __restrict__ DA)
{
    int t = blockIdx.x * 256 + threadIdx.x;
    if (t < Nn * Nn) DA[t] = sigmoidf_(fmaf(*pw, dis[t], *pb));
}

// ---------- edge embed (once): ef_bf[row][col] = edge_fea[row][:41] . WeT[:,col] + be[col]
__global__ __launch_bounds__(256) void k_ef(
    const float* __restrict__ edge_fea, const float* __restrict__ WeT,
    const float* __restrict__ be, __hip_bfloat16* __restrict__ ef_bf)
{
    int row0 = blockIdx.x * 4;
    __shared__ float es[4 * OEF];
    int t = threadIdx.x;
    for (int c = t; c < 4 * OEF; c += 256) es[c] = edge_fea[(size_t)row0 * OEF + c];
    __syncthreads();
    int r = t >> 6, col = t & 63;
    const float* er = &es[r * OEF];
    float a = be[col];
    #pragma unroll
    for (int i = 0; i < OEF; i++) a = fmaf(er[i], WeT[i * EF + col], a);
    ef_bf[(size_t)(row0 + r) * EF + col] = to_bf16(a);
}

// ---------- node embed: nf0 = node_fea @ Wn^T + bn (bf16 out) ----------
__global__ __launch_bounds__(128) void k_embed_node(
    const float* __restrict__ x, const float* __restrict__ WnT,
    const float* __restrict__ bn, __hip_bfloat16* __restrict__ out)
{
    int node = blockIdx.x;
    int o = threadIdx.x;
    __shared__ float xs[ONF];
    if (o < ONF) xs[o] = x[node * ONF + o];
    __syncthreads();
    float a = bn[o];
    #pragma unroll
    for (int i = 0; i < ONF; i++) a = fmaf(xs[i], WnT[i * NF + o], a);
    out[node * NF + o] = to_bf16(a);
}

// ---------- conv layer: MFMA ----------
// 4 nodes/block, A-tile 64x320 bf16 in LDS; B from global bf16 Wswz in
// fragment order (coalesced 1KB loads), register double-buffered.
template<bool PRECOMP>
__global__ __launch_bounds__(256, 3) void k_conv_mfma(
    const __hip_bfloat16* __restrict__ nf_in,   // [B*N][NF] bf16
    const float* __restrict__ edge_fea,         // [B*N*M][OEF] f32  (PRECOMP=false)
    const __hip_bfloat16* __restrict__ ef_bf,   // [B*N*M][EF] bf16  (PRECOMP=true)
    const int*   __restrict__ eidx,             // [B*N][M]
    const float* __restrict__ WeT,              // [OEF][EF] f32     (PRECOMP=false)
    const float* __restrict__ be,               // [EF]              (PRECOMP=false)
    const __hip_bfloat16* __restrict__ Wb,      // swizzled [16][10][64][8] bf16
    const float* __restrict__ bias,             // [ODIM]
    const float* __restrict__ palpha,
    __hip_bfloat16* __restrict__ nf_out)        // [B*N][NF] bf16
{
    constexpr int LDA = 328;                    // bf16 elems; 656B rows keep 16B align
    __shared__ __hip_bfloat16 A_s[64 * LDA];    // 41984 B
    __shared__ int idx_s[64];
    __shared__ float e_s[PRECOMP ? 1 : 64 * OEF];
    __shared__ float W_s[PRECOMP ? 1 : OEF * EF];

    const int node0 = blockIdx.x * 4;
    const int b = node0 >> 8;
    const int t = threadIdx.x;

    if (t < 64) idx_s[t] = eidx[node0 * Mm + t];
    if (!PRECOMP) {
        for (int c = t; c < 64 * OEF; c += 256) e_s[c] = edge_fea[(size_t)(node0 * Mm) * OEF + c];
        for (int c = t; c < OEF * EF; c += 256) W_s[c] = WeT[c];
    }
    __syncthreads();

    // stage self (k 0..127) + gathered (k 128..255): 2048 chunks of 16B
    for (int c = t; c < 2048; c += 256) {
        int part = c >> 10;          // 0 self, 1 gathered
        int rem  = c & 1023;
        int row  = rem >> 4;         // 0..63
        int off  = (rem & 15) << 3;  // 0..120 step 8 (bf16 elems)
        int src_node;
        if (part == 0) src_node = node0 + (row >> 4);
        else { int j = idx_s[row]; j = j < 0 ? 0 : j; src_node = (b << 8) + j; }
        *(uint4*)(A_s + row * LDA + part * NF + off) =
            *(const uint4*)(nf_in + src_node * NF + off);
    }
    // stage edge-embed (k 256..319)
    if (PRECOMP) {
        for (int c = t; c < 512; c += 256) {
            int row = c >> 3, off = (c & 7) << 3;
            *(uint4*)(A_s + row * LDA + 2 * NF + off) =
                *(const uint4*)(ef_bf + (size_t)(node0 * Mm + row) * EF + off);
        }
    } else {
        for (int c = t; c < 64 * EF; c += 256) {
            int row = c >> 6, col = c & 63;
            float a = be[col];
            #pragma unroll
            for (int i = 0; i < OEF; i++) a = fmaf(e_s[row * OEF + i], W_s[i * EF + col], a);
            A_s[row * LDA + 2 * NF + col] = to_bf16(a);
        }
    }
    __syncthreads();

    const int wv = t >> 6, lane = t & 63;
    const int q = lane >> 4, ln16 = lane & 15;

    // acc[mt][p]: mt = node (M-tile), p = tile pair index
    f32x4 accF[4][2], accC[4][2];
    #pragma unroll
    for (int p = 0; p < 2; p++) {
        int colF = (2 * wv + p) * 16 + ln16;
        float bF = bias[colF], bC = bias[colF + NF];
        #pragma unroll
        for (int mt = 0; mt < 4; mt++) {
            accF[mt][p] = (f32x4){bF, bF, bF, bF};
            accC[mt][p] = (f32x4){bC, bC, bC, bC};
        }
    }

    // B pointers: tile stride = 10*64*8 = 5120 elems; k0 stride = 512 elems
    const __hip_bfloat16* WF0 = Wb + ((size_t)(2 * wv) * 5120) + (lane << 3);
    const __hip_bfloat16* WF1 = WF0 + 5120;
    const __hip_bfloat16* WC0 = WF0 + 8 * 5120;
    const __hip_bfloat16* WC1 = WC0 + 5120;

    short8 cF0 = *(const short8*)WF0;
    short8 cF1 = *(const short8*)WF1;
    short8 cC0 = *(const short8*)WC0;
    short8 cC1 = *(const short8*)WC1;

    #pragma unroll
    for (int k0 = 0; k0 < 10; k0++) {
        short8 nF0, nF1, nC0, nC1;
        if (k0 < 9) {
            nF0 = *(const short8*)(WF0 + (k0 + 1) * 512);
            nF1 = *(const short8*)(WF1 + (k0 + 1) * 512);
            nC0 = *(const short8*)(WC0 + (k0 + 1) * 512);
            nC1 = *(const short8*)(WC1 + (k0 + 1) * 512);
        }
        short8 af[4];
        #pragma unroll
        for (int mt = 0; mt < 4; mt++)
            af[mt] = *(const short8*)(A_s + (16 * mt + ln16) * LDA + k0 * 32 + q * 8);
        #pragma unroll
        for (int mt = 0; mt < 4; mt++) {
            accF[mt][0] = __builtin_amdgcn_mfma_f32_16x16x32_bf16(af[mt], cF0, accF[mt][0], 0, 0, 0);
            accF[mt][1] = __builtin_amdgcn_mfma_f32_16x16x32_bf16(af[mt], cF1, accF[mt][1], 0, 0, 0);
            accC[mt][0] = __builtin_amdgcn_mfma_f32_16x16x32_bf16(af[mt], cC0, accC[mt][0], 0, 0, 0);
            accC[mt][1] = __builtin_amdgcn_mfma_f32_16x16x32_bf16(af[mt], cC1, accC[mt][1], 0, 0, 0);
        }
        cF0 = nF0; cF1 = nF1; cC0 = nC0; cC1 = nC1;
    }

    // epilogue: filter = sigmoid(gF)*mask, core = softplus(gC); sum over m; softplus(alpha*self + sum)
    const float alpha = *palpha;
    #pragma unroll
    for (int mt = 0; mt < 4; mt++) {
        const int gnode = node0 + mt;
        #pragma unroll
        for (int p = 0; p < 2; p++) {
            float partial = 0.0f;
            #pragma unroll
            for (int r = 0; r < 4; r++) {
                int m = q * 4 + r;
                bool msk = idx_s[mt * 16 + m] >= 0;
                float f = sigmoidf_(accF[mt][p][r]);
                float c = softplusf_(accC[mt][p][r]);
                partial += msk ? f * c : 0.0f;
            }
            partial += __shfl_xor(partial, 16);
            partial += __shfl_xor(partial, 32);
            if (q == 0) {
                int col = (2 * wv + p) * 16 + ln16;
                float self = __bfloat162float(nf_in[gnode * NF + col]);
                nf_out[gnode * NF + col] = to_bf16(softplusf_(fmaf(alpha, self, partial)));
            }
        }
    }
}

// ---------- final linear: out[:, :, 0:64] = nf3 @ Wf^T + bf (f32 out) ----------
__global__ __launch_bounds__(256) void k_final(
    const __hip_bfloat16* __restrict__ nf, const float* __restrict__ WfT,
    const float* __restrict__ bfv, float* __restrict__ out)
{
    int node4 = blockIdx.x * 4;
    int e = threadIdx.x >> 6, f = threadIdx.x & 63;
    __shared__ float xs[4 * NF];
    for (int k = threadIdx.x; k < 4 * NF; k += 256) xs[k] = __bfloat162float(nf[node4 * NF + k]);
    __syncthreads();
    float a = bfv[f];
    const float* xr = &xs[e * NF];
    #pragma unroll
    for (int i = 0; i < NF; i++) a = fmaf(xr[i], WfT[i * (FINAL / 2) + f], a);
    out[(node4 + e) * FINAL + f] = a;
}

// ---------- node1: out[:, :, 64:128] = DA @ out[:, :, 0:64] (per batch) ----------
__global__ __launch_bounds__(256) void k_node1(
    const float* __restrict__ DA, float* __restrict__ out)
{
    int pair = blockIdx.x * 4 + (threadIdx.x >> 6);  // b*Nn + i
    int f = threadIdx.x & 63;
    int b = pair >> 8, i = pair & 255;
    const float* DArow = DA + i * Nn;
    const float* obase = out + (size_t)b * Nn * FINAL;
    float acc = 0.0f;
    for (int j = 0; j < Nn; j++) acc = fmaf(DArow[j], obase[j * FINAL + f], acc);
    out[(size_t)pair * FINAL + (FINAL / 2) + f] = acc;
}

extern "C" void kernel_launch(void* const* d_in, const int* in_sizes, int n_in,
                              void* d_out, int out_size, void* d_ws, size_t ws_size,
                              hipStream_t stream)
{
    const float* node_fea = (const float*)d_in[0];
    const float* edge_fea = (const float*)d_in[1];
    const int*   eidx     = (const int*)  d_in[2];
    const float* dis      = (const float*)d_in[3];
    const float* Wn = (const float*)d_in[4];
    const float* bn = (const float*)d_in[5];
    const float* We = (const float*)d_in[6];
    const float* be = (const float*)d_in[7];
    const float* W1 = (const float*)d_in[8];
    const float* b1 = (const float*)d_in[9];
    const float* a1 = (const float*)d_in[10];
    const float* W2 = (const float*)d_in[11];
    const float* b2 = (const float*)d_in[12];
    const float* a2 = (const float*)d_in[13];
    const float* W3 = (const float*)d_in[14];
    const float* b3 = (const float*)d_in[15];
    const float* a3 = (const float*)d_in[16];
    const float* Wf = (const float*)d_in[17];
    const float* bf = (const float*)d_in[18];
    const float* DAw = (const float*)d_in[19];
    const float* DAb = (const float*)d_in[20];
    float* out = (float*)d_out;

    // workspace layout (bytes, 256-aligned blocks)
    char* base = (char*)d_ws;
    size_t off = 0;
    auto alloc = [&](size_t bytes) { char* p = base + off; off = (off + bytes + 255) & ~(size_t)255; return p; };
    __hip_bfloat16* nfA = (__hip_bfloat16*)alloc((size_t)Bb * Nn * NF * 2);
    __hip_bfloat16* nfB = (__hip_bfloat16*)alloc((size_t)Bb * Nn * NF * 2);
    __hip_bfloat16* W1b = (__hip_bfloat16*)alloc((size_t)ODIM * KDIM * 2);
    __hip_bfloat16* W2b = (__hip_bfloat16*)alloc((size_t)ODIM * KDIM * 2);
    __hip_bfloat16* W3b = (__hip_bfloat16*)alloc((size_t)ODIM * KDIM * 2);
    float* WnT   = (float*)alloc((size_t)ONF * NF * 4);
    float* WeT   = (float*)alloc((size_t)OEF * EF * 4);
    float* WfT   = (float*)alloc((size_t)NF * (FINAL / 2) * 4);
    float* DAbuf = (float*)alloc((size_t)Nn * Nn * 4);
    __hip_bfloat16* efb = (__hip_bfloat16*)alloc((size_t)Bb * Nn * Mm * EF * 2);  // 33.5 MB
    const bool precomp = (ws_size >= off);   // use ef precompute only if ws fits it

    // prep
    hipLaunchKernelGGL(k_transpose, dim3((NF * ONF + 255) / 256), dim3(256), 0, stream, Wn, WnT, NF, ONF);
    hipLaunchKernelGGL(k_transpose, dim3((EF * OEF + 255) / 256), dim3(256), 0, stream, We, WeT, EF, OEF);
    hipLaunchKernelGGL(k_transpose, dim3(((FINAL / 2) * NF + 255) / 256), dim3(256), 0, stream, Wf, WfT, FINAL / 2, NF);
    hipLaunchKernelGGL(k_wswz, dim3((ODIM * KDIM + 255) / 256), dim3(256), 0, stream, W1, W1b);
    hipLaunchKernelGGL(k_wswz, dim3((ODIM * KDIM + 255) / 256), dim3(256), 0, stream, W2, W2b);
    hipLaunchKernelGGL(k_wswz, dim3((ODIM * KDIM + 255) / 256), dim3(256), 0, stream, W3, W3b);
    hipLaunchKernelGGL(k_da, dim3((Nn * Nn + 255) / 256), dim3(256), 0, stream, dis, DAw, DAb, DAbuf);

    if (precomp)
        hipLaunchKernelGGL(k_ef, dim3(Bb * Nn * Mm / 4), dim3(256), 0, stream, edge_fea, WeT, be, efb);

    hipLaunchKernelGGL(k_embed_node, dim3(Bb * Nn), dim3(128), 0, stream, node_fea, WnT, bn, nfA);

    if (precomp) {
        hipLaunchKernelGGL((k_conv_mfma<true>), dim3(Bb * Nn / 4), dim3(256), 0, stream,
                           nfA, edge_fea, efb, eidx, WeT, be, W1b, b1, a1, nfB);
        hipLaunchKernelGGL((k_conv_mfma<true>), dim3(Bb * Nn / 4), dim3(256), 0, stream,
                           nfB, edge_fea, efb, eidx, WeT, be, W2b, b2, a2, nfA);
        hipLaunchKernelGGL((k_conv_mfma<true>), dim3(Bb * Nn / 4), dim3(256), 0, stream,
                           nfA, edge_fea, efb, eidx, WeT, be, W3b, b3, a3, nfB);
    } else {
        hipLaunchKernelGGL((k_conv_mfma<false>), dim3(Bb * Nn / 4), dim3(256), 0, stream,
                           nfA, edge_fea, efb, eidx, WeT, be, W1b, b1, a1, nfB);
        hipLaunchKernelGGL((k_conv_mfma<false>), dim3(Bb * Nn / 4), dim3(256), 0, stream,
                           nfB, edge_fea, efb, eidx, WeT, be, W2b, b2, a2, nfA);
        hipLaunchKernelGGL((k_conv_mfma<false>), dim3(Bb * Nn / 4), dim3(256), 0, stream,
                           nfA, edge_fea, efb, eidx, WeT, be, W3b, b3, a3, nfB);
    }

    hipLaunchKernelGGL(k_final, dim3(Bb * Nn / 4), dim3(256), 0, stream, nfB, WfT, bf, out);
    hipLaunchKernelGGL(k_node1, dim3(Bb * Nn / 4), dim3(256), 0, stream, DAbuf, out);
}

// Round 4
// 461.348 us; speedup vs baseline: 6.0385x; 1.1308x over previous
//
#include <hip/hip_runtime.h>
#include <hip/hip_bf16.h>
#include <math.h>

#define Bb   64
#define Nn   256
#define Mm   16
#define ONF  92
#define OEF  41
#define NF   128
#define EF   64
#define KDIM 320   // 2*NF + EF
#define ODIM 256   // 2*NF
#define FINAL 128

typedef __attribute__((ext_vector_type(8))) short short8;
typedef __attribute__((ext_vector_type(4))) float f32x4;

__device__ __forceinline__ float sigmoidf_(float x) {
    float e = __expf(-x);
    return __builtin_amdgcn_rcpf(1.0f + e);
}
__device__ __forceinline__ float softplusf_(float x) {
    return fmaxf(x, 0.0f) + __logf(1.0f + __expf(-fabsf(x)));
}
__device__ __forceinline__ __hip_bfloat16 to_bf16(float x) { return __float2bfloat16(x); }

// ---------- tiny prep kernels ----------
// in: [O][I] -> out: [I][O]  (f32)
__global__ void k_transpose(const float* __restrict__ in, float* __restrict__ out, int O, int I)
{
    int t = blockIdx.x * 256 + threadIdx.x;
    if (t < O * I) {
        int o = t / I, i = t - o * I;
        out[i * O + o] = in[t];
    }
}

// W [ODIM][KDIM] f32 -> bf16 in MFMA-B-fragment order (conv weights, K exact):
// dst elem = ((tile*10 + k0)*64 + q*16 + ln16)*8 + j ; n=tile*16+ln16, k=k0*32+q*8+j
__global__ void k_wswz(const float* __restrict__ in, __hip_bfloat16* __restrict__ out)
{
    int t = blockIdx.x * 256 + threadIdx.x;
    if (t < ODIM * KDIM) {
        int n = t / KDIM, k = t - n * KDIM;
        int tile = n >> 4, ln16 = n & 15;
        int k0 = k >> 5, q = (k >> 3) & 3, j = k & 7;
        out[(size_t)(((tile * 10 + k0) << 6) + (q << 4) + ln16) * 8 + j] = to_bf16(in[t]);
    }
}

// W [O][I] f32 -> bf16 B-fragment order with K padded to K0*32 (zeros).
// dst layout: [tile(O/16)][k0(K0)][lane(64)][8]
__global__ void k_wswz_pad(const float* __restrict__ in, __hip_bfloat16* __restrict__ out,
                           int O, int I, int K0)
{
    int t = blockIdx.x * 256 + threadIdx.x;
    int total = (O >> 4) * K0 * 512;
    if (t < total) {
        int j = t & 7;
        int u = t >> 3;
        int lane = u & 63;
        int ln16 = lane & 15, q = lane >> 4;
        int v = u >> 6;
        int k0 = v % K0, tile = v / K0;
        int n = tile * 16 + ln16, k = k0 * 32 + q * 8 + j;
        out[t] = (k < I) ? to_bf16(in[n * I + k]) : to_bf16(0.0f);
    }
}

__global__ void k_da(const float* __restrict__ dis, const float* __restrict__ pw,
                     const float* __restrict__ pb, float* __restrict__ DA)
{
    int t = blockIdx.x * 256 + threadIdx.x;
    if (t < Nn * Nn) DA[t] = sigmoidf_(fmaf(*pw, dis[t], *pb));
}

// ---------- generic MFMA embed: Y[r][c] = X[r][:KIN] . W[c][:KIN] + bias[c] ----------
// 64 rows/block; A staged f32->bf16 into LDS in A-fragment order (K padded to K0*32).
// Bswz: [NCOLS/16][K0][64][8] fragment-order bf16 (zero-padded).
template<int KIN, int K0, int NCOLS>
__global__ __launch_bounds__(256) void k_emb(
    const float* __restrict__ X, const __hip_bfloat16* __restrict__ Bswz,
    const float* __restrict__ bias, __hip_bfloat16* __restrict__ Y)
{
    constexpr int KP = K0 * 32;
    constexpr int TPW = NCOLS / 64;   // col-tiles per wave
    __shared__ __hip_bfloat16 A_s[4 * K0 * 512];

    const int row0 = blockIdx.x * 64;
    const int t = threadIdx.x;

    // stage X -> A_s (fragment order), zero the K-pad
    for (int c = t; c < 64 * KP; c += 256) {
        int row = c / KP, k = c - row * KP;
        float v = (k < KIN) ? X[(size_t)(row0 + row) * KIN + k] : 0.0f;
        int mt = row >> 4, ln16 = row & 15;
        int k0 = k >> 5, q = (k >> 3) & 3, j = k & 7;
        A_s[(((mt * K0 + k0) << 6) + (q << 4) + ln16) * 8 + j] = to_bf16(v);
    }
    __syncthreads();

    const int wv = t >> 6, lane = t & 63;
    const int q = lane >> 4, ln16 = lane & 15;

    f32x4 acc[4][TPW];
    #pragma unroll
    for (int p = 0; p < TPW; p++) {
        float bv = bias[(wv * TPW + p) * 16 + ln16];
        #pragma unroll
        for (int mt = 0; mt < 4; mt++) acc[mt][p] = (f32x4){bv, bv, bv, bv};
    }

    // B fragments (all K0*TPW of them) up front
    short8 bw[TPW][K0];
    #pragma unroll
    for (int p = 0; p < TPW; p++)
        #pragma unroll
        for (int k0 = 0; k0 < K0; k0++)
            bw[p][k0] = *(const short8*)(Bswz + ((size_t)((wv * TPW + p) * K0 + k0) << 9) + (lane << 3));

    #pragma unroll
    for (int k0 = 0; k0 < K0; k0++) {
        short8 af[4];
        #pragma unroll
        for (int mt = 0; mt < 4; mt++)
            af[mt] = *(const short8*)(A_s + (((mt * K0 + k0) << 6) + lane) * 8);
        #pragma unroll
        for (int mt = 0; mt < 4; mt++)
            #pragma unroll
            for (int p = 0; p < TPW; p++)
                acc[mt][p] = __builtin_amdgcn_mfma_f32_16x16x32_bf16(af[mt], bw[p][k0], acc[mt][p], 0, 0, 0);
    }

    #pragma unroll
    for (int mt = 0; mt < 4; mt++)
        #pragma unroll
        for (int p = 0; p < TPW; p++) {
            int col = (wv * TPW + p) * 16 + ln16;
            #pragma unroll
            for (int r = 0; r < 4; r++) {
                int row = row0 + mt * 16 + q * 4 + r;
                Y[(size_t)row * NCOLS + col] = to_bf16(acc[mt][p][r]);
            }
        }
}

// ---------- conv layer: MFMA ----------
// 4 nodes/block, A-tile 64x320 bf16 in LDS; B from global bf16 Wswz in
// fragment order (coalesced 1KB loads), register double-buffered.
template<bool PRECOMP>
__global__ __launch_bounds__(256, 3) void k_conv_mfma(
    const __hip_bfloat16* __restrict__ nf_in,   // [B*N][NF] bf16
    const float* __restrict__ edge_fea,         // [B*N*M][OEF] f32  (PRECOMP=false)
    const __hip_bfloat16* __restrict__ ef_bf,   // [B*N*M][EF] bf16  (PRECOMP=true)
    const int*   __restrict__ eidx,             // [B*N][M]
    const float* __restrict__ WeT,              // [OEF][EF] f32     (PRECOMP=false)
    const float* __restrict__ be,               // [EF]              (PRECOMP=false)
    const __hip_bfloat16* __restrict__ Wb,      // swizzled [16][10][64][8] bf16
    const float* __restrict__ bias,             // [ODIM]
    const float* __restrict__ palpha,
    __hip_bfloat16* __restrict__ nf_out)        // [B*N][NF] bf16
{
    constexpr int LDA = 328;                    // bf16 elems; 656B rows keep 16B align
    __shared__ __hip_bfloat16 A_s[64 * LDA];    // 41984 B
    __shared__ int idx_s[64];
    __shared__ float e_s[PRECOMP ? 1 : 64 * OEF];
    __shared__ float W_s[PRECOMP ? 1 : OEF * EF];

    const int node0 = blockIdx.x * 4;
    const int b = node0 >> 8;
    const int t = threadIdx.x;

    if (t < 64) idx_s[t] = eidx[node0 * Mm + t];
    if (!PRECOMP) {
        for (int c = t; c < 64 * OEF; c += 256) e_s[c] = edge_fea[(size_t)(node0 * Mm) * OEF + c];
        for (int c = t; c < OEF * EF; c += 256) W_s[c] = WeT[c];
    }
    __syncthreads();

    // stage self (k 0..127) + gathered (k 128..255): 2048 chunks of 16B
    for (int c = t; c < 2048; c += 256) {
        int part = c >> 10;          // 0 self, 1 gathered
        int rem  = c & 1023;
        int row  = rem >> 4;         // 0..63
        int off  = (rem & 15) << 3;  // 0..120 step 8 (bf16 elems)
        int src_node;
        if (part == 0) src_node = node0 + (row >> 4);
        else { int j = idx_s[row]; j = j < 0 ? 0 : j; src_node = (b << 8) + j; }
        *(uint4*)(A_s + row * LDA + part * NF + off) =
            *(const uint4*)(nf_in + src_node * NF + off);
    }
    // stage edge-embed (k 256..319)
    if (PRECOMP) {
        for (int c = t; c < 512; c += 256) {
            int row = c >> 3, off = (c & 7) << 3;
            *(uint4*)(A_s + row * LDA + 2 * NF + off) =
                *(const uint4*)(ef_bf + (size_t)(node0 * Mm + row) * EF + off);
        }
    } else {
        for (int c = t; c < 64 * EF; c += 256) {
            int row = c >> 6, col = c & 63;
            float a = be[col];
            #pragma unroll
            for (int i = 0; i < OEF; i++) a = fmaf(e_s[row * OEF + i], W_s[i * EF + col], a);
            A_s[row * LDA + 2 * NF + col] = to_bf16(a);
        }
    }
    __syncthreads();

    const int wv = t >> 6, lane = t & 63;
    const int q = lane >> 4, ln16 = lane & 15;

    // acc[mt][p]: mt = node (M-tile), p = tile pair index
    f32x4 accF[4][2], accC[4][2];
    #pragma unroll
    for (int p = 0; p < 2; p++) {
        int colF = (2 * wv + p) * 16 + ln16;
        float bF = bias[colF], bC = bias[colF + NF];
        #pragma unroll
        for (int mt = 0; mt < 4; mt++) {
            accF[mt][p] = (f32x4){bF, bF, bF, bF};
            accC[mt][p] = (f32x4){bC, bC, bC, bC};
        }
    }

    // B pointers: tile stride = 10*64*8 = 5120 elems; k0 stride = 512 elems
    const __hip_bfloat16* WF0 = Wb + ((size_t)(2 * wv) * 5120) + (lane << 3);
    const __hip_bfloat16* WF1 = WF0 + 5120;
    const __hip_bfloat16* WC0 = WF0 + 8 * 5120;
    const __hip_bfloat16* WC1 = WC0 + 5120;

    short8 cF0 = *(const short8*)WF0;
    short8 cF1 = *(const short8*)WF1;
    short8 cC0 = *(const short8*)WC0;
    short8 cC1 = *(const short8*)WC1;

    #pragma unroll
    for (int k0 = 0; k0 < 10; k0++) {
        short8 nF0, nF1, nC0, nC1;
        if (k0 < 9) {
            nF0 = *(const short8*)(WF0 + (k0 + 1) * 512);
            nF1 = *(const short8*)(WF1 + (k0 + 1) * 512);
            nC0 = *(const short8*)(WC0 + (k0 + 1) * 512);
            nC1 = *(const short8*)(WC1 + (k0 + 1) * 512);
        }
        short8 af[4];
        #pragma unroll
        for (int mt = 0; mt < 4; mt++)
            af[mt] = *(const short8*)(A_s + (16 * mt + ln16) * LDA + k0 * 32 + q * 8);
        #pragma unroll
        for (int mt = 0; mt < 4; mt++) {
            accF[mt][0] = __builtin_amdgcn_mfma_f32_16x16x32_bf16(af[mt], cF0, accF[mt][0], 0, 0, 0);
            accF[mt][1] = __builtin_amdgcn_mfma_f32_16x16x32_bf16(af[mt], cF1, accF[mt][1], 0, 0, 0);
            accC[mt][0] = __builtin_amdgcn_mfma_f32_16x16x32_bf16(af[mt], cC0, accC[mt][0], 0, 0, 0);
            accC[mt][1] = __builtin_amdgcn_mfma_f32_16x16x32_bf16(af[mt], cC1, accC[mt][1], 0, 0, 0);
        }
        cF0 = nF0; cF1 = nF1; cC0 = nC0; cC1 = nC1;
    }

    // epilogue: filter = sigmoid(gF)*mask, core = softplus(gC); sum over m; softplus(alpha*self + sum)
    const float alpha = *palpha;
    #pragma unroll
    for (int mt = 0; mt < 4; mt++) {
        const int gnode = node0 + mt;
        #pragma unroll
        for (int p = 0; p < 2; p++) {
            float partial = 0.0f;
            #pragma unroll
            for (int r = 0; r < 4; r++) {
                int m = q * 4 + r;
                bool msk = idx_s[mt * 16 + m] >= 0;
                float f = sigmoidf_(accF[mt][p][r]);
                float c = softplusf_(accC[mt][p][r]);
                partial += msk ? f * c : 0.0f;
            }
            partial += __shfl_xor(partial, 16);
            partial += __shfl_xor(partial, 32);
            if (q == 0) {
                int col = (2 * wv + p) * 16 + ln16;
                float self = __bfloat162float(nf_in[gnode * NF + col]);
                nf_out[gnode * NF + col] = to_bf16(softplusf_(fmaf(alpha, self, partial)));
            }
        }
    }
}

// ---------- final linear: out[:, :, 0:64] = nf3 @ Wf^T + bf (f32 out) ----------
__global__ __launch_bounds__(256) void k_final(
    const __hip_bfloat16* __restrict__ nf, const float* __restrict__ WfT,
    const float* __restrict__ bfv, float* __restrict__ out)
{
    int node4 = blockIdx.x * 4;
    int e = threadIdx.x >> 6, f = threadIdx.x & 63;
    __shared__ float xs[4 * NF];
    for (int k = threadIdx.x; k < 4 * NF; k += 256) xs[k] = __bfloat162float(nf[node4 * NF + k]);
    __syncthreads();
    float a = bfv[f];
    const float* xr = &xs[e * NF];
    #pragma unroll
    for (int i = 0; i < NF; i++) a = fmaf(xr[i], WfT[i * (FINAL / 2) + f], a);
    out[(node4 + e) * FINAL + f] = a;
}

// ---------- node1: out[:, :, 64:128] = DA @ out[:, :, 0:64] (per batch) ----------
__global__ __launch_bounds__(256) void k_node1(
    const float* __restrict__ DA, float* __restrict__ out)
{
    int pair = blockIdx.x * 4 + (threadIdx.x >> 6);  // b*Nn + i
    int f = threadIdx.x & 63;
    int b = pair >> 8, i = pair & 255;
    const float* DArow = DA + i * Nn;
    const float* obase = out + (size_t)b * Nn * FINAL;
    float acc = 0.0f;
    for (int j = 0; j < Nn; j++) acc = fmaf(DArow[j], obase[j * FINAL + f], acc);
    out[(size_t)pair * FINAL + (FINAL / 2) + f] = acc;
}

extern "C" void kernel_launch(void* const* d_in, const int* in_sizes, int n_in,
                              void* d_out, int out_size, void* d_ws, size_t ws_size,
                              hipStream_t stream)
{
    const float* node_fea = (const float*)d_in[0];
    const float* edge_fea = (const float*)d_in[1];
    const int*   eidx     = (const int*)  d_in[2];
    const float* dis      = (const float*)d_in[3];
    const float* Wn = (const float*)d_in[4];
    const float* bn = (const float*)d_in[5];
    const float* We = (const float*)d_in[6];
    const float* be = (const float*)d_in[7];
    const float* W1 = (const float*)d_in[8];
    const float* b1 = (const float*)d_in[9];
    const float* a1 = (const float*)d_in[10];
    const float* W2 = (const float*)d_in[11];
    const float* b2 = (const float*)d_in[12];
    const float* a2 = (const float*)d_in[13];
    const float* W3 = (const float*)d_in[14];
    const float* b3 = (const float*)d_in[15];
    const float* a3 = (const float*)d_in[16];
    const float* Wf = (const float*)d_in[17];
    const float* bf = (const float*)d_in[18];
    const float* DAw = (const float*)d_in[19];
    const float* DAb = (const float*)d_in[20];
    float* out = (float*)d_out;

    // workspace layout (bytes, 256-aligned blocks)
    char* base = (char*)d_ws;
    size_t off = 0;
    auto alloc = [&](size_t bytes) { char* p = base + off; off = (off + bytes + 255) & ~(size_t)255; return p; };
    __hip_bfloat16* nfA = (__hip_bfloat16*)alloc((size_t)Bb * Nn * NF * 2);
    __hip_bfloat16* nfB = (__hip_bfloat16*)alloc((size_t)Bb * Nn * NF * 2);
    __hip_bfloat16* W1b = (__hip_bfloat16*)alloc((size_t)ODIM * KDIM * 2);
    __hip_bfloat16* W2b = (__hip_bfloat16*)alloc((size_t)ODIM * KDIM * 2);
    __hip_bfloat16* W3b = (__hip_bfloat16*)alloc((size_t)ODIM * KDIM * 2);
    float* WnT   = (float*)alloc((size_t)ONF * NF * 4);   // unused now, kept for layout stability
    float* WeT   = (float*)alloc((size_t)OEF * EF * 4);   // fallback path
    float* WfT   = (float*)alloc((size_t)NF * (FINAL / 2) * 4);
    float* DAbuf = (float*)alloc((size_t)Nn * Nn * 4);
    __hip_bfloat16* Wnb = (__hip_bfloat16*)alloc((size_t)(NF / 16) * 3 * 512 * 2);  // node embed Bswz, K0=3
    __hip_bfloat16* Web = (__hip_bfloat16*)alloc((size_t)(EF / 16) * 2 * 512 * 2);  // edge embed Bswz, K0=2
    __hip_bfloat16* efb = (__hip_bfloat16*)alloc((size_t)Bb * Nn * Mm * EF * 2);    // 33.5 MB
    const bool precomp = (ws_size >= off);   // use ef precompute only if ws fits it

    // prep
    hipLaunchKernelGGL(k_transpose, dim3((EF * OEF + 255) / 256), dim3(256), 0, stream, We, WeT, EF, OEF);
    hipLaunchKernelGGL(k_transpose, dim3(((FINAL / 2) * NF + 255) / 256), dim3(256), 0, stream, Wf, WfT, FINAL / 2, NF);
    hipLaunchKernelGGL(k_wswz, dim3((ODIM * KDIM + 255) / 256), dim3(256), 0, stream, W1, W1b);
    hipLaunchKernelGGL(k_wswz, dim3((ODIM * KDIM + 255) / 256), dim3(256), 0, stream, W2, W2b);
    hipLaunchKernelGGL(k_wswz, dim3((ODIM * KDIM + 255) / 256), dim3(256), 0, stream, W3, W3b);
    hipLaunchKernelGGL(k_wswz_pad, dim3(((NF / 16) * 3 * 512 + 255) / 256), dim3(256), 0, stream, Wn, Wnb, NF, ONF, 3);
    hipLaunchKernelGGL(k_wswz_pad, dim3(((EF / 16) * 2 * 512 + 255) / 256), dim3(256), 0, stream, We, Web, EF, OEF, 2);
    hipLaunchKernelGGL(k_da, dim3((Nn * Nn + 255) / 256), dim3(256), 0, stream, dis, DAw, DAb, DAbuf);

    // embeds (MFMA)
    if (precomp)
        hipLaunchKernelGGL((k_emb<OEF, 2, EF>), dim3(Bb * Nn * Mm / 64), dim3(256), 0, stream,
                           edge_fea, Web, be, efb);
    hipLaunchKernelGGL((k_emb<ONF, 3, NF>), dim3(Bb * Nn / 64), dim3(256), 0, stream,
                       node_fea, Wnb, bn, nfA);

    if (precomp) {
        hipLaunchKernelGGL((k_conv_mfma<true>), dim3(Bb * Nn / 4), dim3(256), 0, stream,
                           nfA, edge_fea, efb, eidx, WeT, be, W1b, b1, a1, nfB);
        hipLaunchKernelGGL((k_conv_mfma<true>), dim3(Bb * Nn / 4), dim3(256), 0, stream,
                           nfB, edge_fea, efb, eidx, WeT, be, W2b, b2, a2, nfA);
        hipLaunchKernelGGL((k_conv_mfma<true>), dim3(Bb * Nn / 4), dim3(256), 0, stream,
                           nfA, edge_fea, efb, eidx, WeT, be, W3b, b3, a3, nfB);
    } else {
        hipLaunchKernelGGL((k_conv_mfma<false>), dim3(Bb * Nn / 4), dim3(256), 0, stream,
                           nfA, edge_fea, efb, eidx, WeT, be, W1b, b1, a1, nfB);
        hipLaunchKernelGGL((k_conv_mfma<false>), dim3(Bb * Nn / 4), dim3(256), 0, stream,
                           nfB, edge_fea, efb, eidx, WeT, be, W2b, b2, a2, nfA);
        hipLaunchKernelGGL((k_conv_mfma<false>), dim3(Bb * Nn / 4), dim3(256), 0, stream,
                           nfA, edge_fea, efb, eidx, WeT, be, W3b, b3, a3, nfB);
    }

    hipLaunchKernelGGL(k_final, dim3(Bb * Nn / 4), dim3(256), 0, stream, nfB, WfT, bf, out);
    hipLaunchKernelGGL(k_node1, dim3(Bb * Nn / 4), dim3(256), 0, stream, DAbuf, out);
}

// Round 5
// 361.710 us; speedup vs baseline: 7.7019x; 1.2755x over previous
//
#include <hip/hip_runtime.h>
#include <hip/hip_bf16.h>
#include <math.h>

#define Bb   64
#define Nn   256
#define Mm   16
#define ONF  92
#define OEF  41
#define NF   128
#define EF   64
#define KDIM 320   // 2*NF + EF
#define ODIM 256   // 2*NF
#define FINAL 128

typedef __attribute__((ext_vector_type(8))) short short8;
typedef __attribute__((ext_vector_type(4))) float f32x4;

__device__ __forceinline__ float sigmoidf_(float x) {
    float e = __expf(-x);
    return __builtin_amdgcn_rcpf(1.0f + e);
}
__device__ __forceinline__ float softplusf_(float x) {
    return fmaxf(x, 0.0f) + __logf(1.0f + __expf(-fabsf(x)));
}
__device__ __forceinline__ __hip_bfloat16 to_bf16(float x) { return __float2bfloat16(x); }

// ---------- tiny prep kernels ----------
// in: [O][I] -> out: [I][O]  (f32) — fallback conv path only
__global__ void k_transpose(const float* __restrict__ in, float* __restrict__ out, int O, int I)
{
    int t = blockIdx.x * 256 + threadIdx.x;
    if (t < O * I) {
        int o = t / I, i = t - o * I;
        out[i * O + o] = in[t];
    }
}

// W [ODIM][KDIM] f32 -> bf16 in MFMA-B-fragment order (conv weights, K exact):
// dst elem = ((tile*10 + k0)*64 + q*16 + ln16)*8 + j ; n=tile*16+ln16, k=k0*32+q*8+j
__global__ void k_wswz(const float* __restrict__ in, __hip_bfloat16* __restrict__ out)
{
    int t = blockIdx.x * 256 + threadIdx.x;
    if (t < ODIM * KDIM) {
        int n = t / KDIM, k = t - n * KDIM;
        int tile = n >> 4, ln16 = n & 15;
        int k0 = k >> 5, q = (k >> 3) & 3, j = k & 7;
        out[(size_t)(((tile * 10 + k0) << 6) + (q << 4) + ln16) * 8 + j] = to_bf16(in[t]);
    }
}

// W [O][I] f32 -> bf16 B-fragment order with K padded to K0*32 (zeros).
// dst layout: [tile(O/16)][k0(K0)][lane(64)][8]
__global__ void k_wswz_pad(const float* __restrict__ in, __hip_bfloat16* __restrict__ out,
                           int O, int I, int K0)
{
    int t = blockIdx.x * 256 + threadIdx.x;
    int total = (O >> 4) * K0 * 512;
    if (t < total) {
        int j = t & 7;
        int u = t >> 3;
        int lane = u & 63;
        int ln16 = lane & 15, q = lane >> 4;
        int v = u >> 6;
        int k0 = v % K0, tile = v / K0;
        int n = tile * 16 + ln16, k = k0 * 32 + q * 8 + j;
        out[t] = (k < I) ? to_bf16(in[n * I + k]) : to_bf16(0.0f);
    }
}

// DA = sigmoid(w*dis+b), emitted directly in bf16 A-fragment order:
// DAf[((itile*8 + k0)*64 + q*16 + ln16)*8 + jj] = DA[i][j], i=itile*16+ln16, j=k0*32+q*8+jj
__global__ void k_da(const float* __restrict__ dis, const float* __restrict__ pw,
                     const float* __restrict__ pb, __hip_bfloat16* __restrict__ DAf)
{
    int t = blockIdx.x * 256 + threadIdx.x;
    if (t < Nn * Nn) {
        int i = t >> 8, jx = t & 255;
        float v = sigmoidf_(fmaf(*pw, dis[t], *pb));
        int itile = i >> 4, ln16 = i & 15;
        int k0 = jx >> 5, q = (jx >> 3) & 3, jj = jx & 7;
        DAf[(size_t)((((itile * 8 + k0) << 6) + (q << 4) + ln16)) * 8 + jj] = to_bf16(v);
    }
}

// ---------- generic MFMA embed: Y[r][c] = X[r][:KIN] . W[c][:KIN] + bias[c] ----------
template<int KIN, int K0, int NCOLS>
__global__ __launch_bounds__(256) void k_emb(
    const float* __restrict__ X, const __hip_bfloat16* __restrict__ Bswz,
    const float* __restrict__ bias, __hip_bfloat16* __restrict__ Y)
{
    constexpr int KP = K0 * 32;
    constexpr int TPW = NCOLS / 64;   // col-tiles per wave
    __shared__ __align__(16) __hip_bfloat16 A_s[4 * K0 * 512];

    const int row0 = blockIdx.x * 64;
    const int t = threadIdx.x;

    for (int c = t; c < 64 * KP; c += 256) {
        int row = c / KP, k = c - row * KP;
        float v = (k < KIN) ? X[(size_t)(row0 + row) * KIN + k] : 0.0f;
        int mt = row >> 4, ln16 = row & 15;
        int k0 = k >> 5, q = (k >> 3) & 3, j = k & 7;
        A_s[(((mt * K0 + k0) << 6) + (q << 4) + ln16) * 8 + j] = to_bf16(v);
    }
    __syncthreads();

    const int wv = t >> 6, lane = t & 63;
    const int q = lane >> 4, ln16 = lane & 15;

    f32x4 acc[4][TPW];
    #pragma unroll
    for (int p = 0; p < TPW; p++) {
        float bv = bias[(wv * TPW + p) * 16 + ln16];
        #pragma unroll
        for (int mt = 0; mt < 4; mt++) acc[mt][p] = (f32x4){bv, bv, bv, bv};
    }

    short8 bw[TPW][K0];
    #pragma unroll
    for (int p = 0; p < TPW; p++)
        #pragma unroll
        for (int k0 = 0; k0 < K0; k0++)
            bw[p][k0] = *(const short8*)(Bswz + ((size_t)((wv * TPW + p) * K0 + k0) << 9) + (lane << 3));

    #pragma unroll
    for (int k0 = 0; k0 < K0; k0++) {
        short8 af[4];
        #pragma unroll
        for (int mt = 0; mt < 4; mt++)
            af[mt] = *(const short8*)(A_s + (((mt * K0 + k0) << 6) + lane) * 8);
        #pragma unroll
        for (int mt = 0; mt < 4; mt++)
            #pragma unroll
            for (int p = 0; p < TPW; p++)
                acc[mt][p] = __builtin_amdgcn_mfma_f32_16x16x32_bf16(af[mt], bw[p][k0], acc[mt][p], 0, 0, 0);
    }

    #pragma unroll
    for (int mt = 0; mt < 4; mt++)
        #pragma unroll
        for (int p = 0; p < TPW; p++) {
            int col = (wv * TPW + p) * 16 + ln16;
            #pragma unroll
            for (int r = 0; r < 4; r++) {
                int row = row0 + mt * 16 + q * 4 + r;
                Y[(size_t)row * NCOLS + col] = to_bf16(acc[mt][p][r]);
            }
        }
}

// ---------- conv layer: MFMA, fragment-order A in LDS (conflict-free) ----------
// A_s slot layout: [mt*10 + k0][lane][8], lane = q*16 + ln16 -> A[m=ln16][k=k0*32+q*8+j]
template<bool PRECOMP>
__global__ __launch_bounds__(256, 3) void k_conv_mfma(
    const __hip_bfloat16* __restrict__ nf_in,   // [B*N][NF] bf16
    const float* __restrict__ edge_fea,         // [B*N*M][OEF] f32  (PRECOMP=false)
    const __hip_bfloat16* __restrict__ ef_bf,   // [B*N*M][EF] bf16  (PRECOMP=true)
    const int*   __restrict__ eidx,             // [B*N][M]
    const float* __restrict__ WeT,              // [OEF][EF] f32     (PRECOMP=false)
    const float* __restrict__ be,               // [EF]              (PRECOMP=false)
    const __hip_bfloat16* __restrict__ Wb,      // swizzled [16][10][64][8] bf16
    const float* __restrict__ bias,             // [ODIM]
    const float* __restrict__ palpha,
    __hip_bfloat16* __restrict__ nf_out)        // [B*N][NF] bf16
{
    __shared__ __align__(16) __hip_bfloat16 A_s[40 * 512];   // 40960 B
    __shared__ int idx_s[64];
    __shared__ float e_s[PRECOMP ? 1 : 64 * OEF];
    __shared__ float W_s[PRECOMP ? 1 : OEF * EF];

    const int node0 = blockIdx.x * 4;
    const int b = node0 >> 8;
    const int t = threadIdx.x;
    const int wv = t >> 6, lane = t & 63;
    const int q = lane >> 4, ln16 = lane & 15;

    if (t < 64) idx_s[t] = eidx[node0 * Mm + t];
    if (!PRECOMP) {
        for (int c = t; c < 64 * OEF; c += 256) e_s[c] = edge_fea[(size_t)(node0 * Mm) * OEF + c];
        for (int c = t; c < OEF * EF; c += 256) W_s[c] = WeT[c];
    }
    __syncthreads();

    // stage A: wave wv handles node mt=wv. Writes are base+lane*16 (conflict-free).
    {
        const int row = (wv << 4) + ln16;          // A-tile row 0..63
        int j = idx_s[row]; j = j < 0 ? 0 : j;
        const __hip_bfloat16* selfp = nf_in + (size_t)(node0 + wv) * NF;
        const __hip_bfloat16* gathp = nf_in + (size_t)((b << 8) + j) * NF;
        #pragma unroll
        for (int k0 = 0; k0 < 4; k0++)
            *(uint4*)(A_s + ((wv * 10 + k0) * 64 + lane) * 8) =
                *(const uint4*)(selfp + k0 * 32 + q * 8);
        #pragma unroll
        for (int k0 = 0; k0 < 4; k0++)
            *(uint4*)(A_s + ((wv * 10 + 4 + k0) * 64 + lane) * 8) =
                *(const uint4*)(gathp + k0 * 32 + q * 8);
        if (PRECOMP) {
            const __hip_bfloat16* efp = ef_bf + (size_t)((node0 << 4) + row) * EF;
            #pragma unroll
            for (int k0 = 0; k0 < 2; k0++)
                *(uint4*)(A_s + ((wv * 10 + 8 + k0) * 64 + lane) * 8) =
                    *(const uint4*)(efp + k0 * 32 + q * 8);
        }
    }
    if (!PRECOMP) {
        for (int c = t; c < 64 * EF; c += 256) {
            int row = c >> 6, col = c & 63;
            float a = be[col];
            #pragma unroll
            for (int i = 0; i < OEF; i++) a = fmaf(e_s[row * OEF + i], W_s[i * EF + col], a);
            int mt = row >> 4, l16 = row & 15;
            int k0 = 8 + (col >> 5), qq = (col >> 3) & 3, jj = col & 7;
            A_s[((mt * 10 + k0) * 64 + qq * 16 + l16) * 8 + jj] = to_bf16(a);
        }
    }
    __syncthreads();

    // acc[mt][p]: mt = node (M-tile), p = tile pair index
    f32x4 accF[4][2], accC[4][2];
    #pragma unroll
    for (int p = 0; p < 2; p++) {
        int colF = (2 * wv + p) * 16 + ln16;
        float bF = bias[colF], bC = bias[colF + NF];
        #pragma unroll
        for (int mt = 0; mt < 4; mt++) {
            accF[mt][p] = (f32x4){bF, bF, bF, bF};
            accC[mt][p] = (f32x4){bC, bC, bC, bC};
        }
    }

    // B pointers: tile stride = 5120 elems; k0 stride = 512 elems
    const __hip_bfloat16* WF0 = Wb + ((size_t)(2 * wv) * 5120) + (lane << 3);
    const __hip_bfloat16* WF1 = WF0 + 5120;
    const __hip_bfloat16* WC0 = WF0 + 8 * 5120;
    const __hip_bfloat16* WC1 = WC0 + 5120;

    short8 cF0 = *(const short8*)WF0;
    short8 cF1 = *(const short8*)WF1;
    short8 cC0 = *(const short8*)WC0;
    short8 cC1 = *(const short8*)WC1;

    #pragma unroll
    for (int k0 = 0; k0 < 10; k0++) {
        short8 nF0, nF1, nC0, nC1;
        if (k0 < 9) {
            nF0 = *(const short8*)(WF0 + (k0 + 1) * 512);
            nF1 = *(const short8*)(WF1 + (k0 + 1) * 512);
            nC0 = *(const short8*)(WC0 + (k0 + 1) * 512);
            nC1 = *(const short8*)(WC1 + (k0 + 1) * 512);
        }
        short8 af[4];
        #pragma unroll
        for (int mt = 0; mt < 4; mt++)
            af[mt] = *(const short8*)(A_s + ((mt * 10 + k0) * 64 + lane) * 8);
        #pragma unroll
        for (int mt = 0; mt < 4; mt++) {
            accF[mt][0] = __builtin_amdgcn_mfma_f32_16x16x32_bf16(af[mt], cF0, accF[mt][0], 0, 0, 0);
            accF[mt][1] = __builtin_amdgcn_mfma_f32_16x16x32_bf16(af[mt], cF1, accF[mt][1], 0, 0, 0);
            accC[mt][0] = __builtin_amdgcn_mfma_f32_16x16x32_bf16(af[mt], cC0, accC[mt][0], 0, 0, 0);
            accC[mt][1] = __builtin_amdgcn_mfma_f32_16x16x32_bf16(af[mt], cC1, accC[mt][1], 0, 0, 0);
        }
        cF0 = nF0; cF1 = nF1; cC0 = nC0; cC1 = nC1;
    }

    // epilogue
    const float alpha = *palpha;
    #pragma unroll
    for (int mt = 0; mt < 4; mt++) {
        const int gnode = node0 + mt;
        #pragma unroll
        for (int p = 0; p < 2; p++) {
            float partial = 0.0f;
            #pragma unroll
            for (int r = 0; r < 4; r++) {
                int m = q * 4 + r;
                bool msk = idx_s[mt * 16 + m] >= 0;
                float f = sigmoidf_(accF[mt][p][r]);
                float c = softplusf_(accC[mt][p][r]);
                partial += msk ? f * c : 0.0f;
            }
            partial += __shfl_xor(partial, 16);
            partial += __shfl_xor(partial, 32);
            if (q == 0) {
                int col = (2 * wv + p) * 16 + ln16;
                float self = __bfloat162float(nf_in[(size_t)gnode * NF + col]);
                nf_out[(size_t)gnode * NF + col] = to_bf16(softplusf_(fmaf(alpha, self, partial)));
            }
        }
    }
}

// ---------- final linear (MFMA): out[:, :, 0:64] = nf3 @ Wf^T + bf ----------
// Also emits XT[b][f][j] bf16 (f-major) for the node1 GEMM's B operand.
__global__ __launch_bounds__(256) void k_final_mfma(
    const __hip_bfloat16* __restrict__ nf, const __hip_bfloat16* __restrict__ Wfb,
    const float* __restrict__ bfv, float* __restrict__ out,
    __hip_bfloat16* __restrict__ XT)
{
    __shared__ __align__(16) __hip_bfloat16 A_s[16 * 512];  // 16 KB
    const int node0 = blockIdx.x * 64;
    const int bloc = node0 >> 8;
    const int t = threadIdx.x;
    const int wv = t >> 6, lane = t & 63;
    const int q = lane >> 4, ln16 = lane & 15;

    const __hip_bfloat16* rowp = nf + (size_t)(node0 + (wv << 4) + ln16) * NF;
    #pragma unroll
    for (int k0 = 0; k0 < 4; k0++)
        *(uint4*)(A_s + ((wv * 4 + k0) * 64 + lane) * 8) =
            *(const uint4*)(rowp + k0 * 32 + q * 8);
    __syncthreads();

    short8 bw[4];
    #pragma unroll
    for (int k0 = 0; k0 < 4; k0++)
        bw[k0] = *(const short8*)(Wfb + ((size_t)(wv * 4 + k0) * 64 + lane) * 8);

    float bv = bfv[wv * 16 + ln16];
    f32x4 acc[4];
    #pragma unroll
    for (int mt = 0; mt < 4; mt++) acc[mt] = (f32x4){bv, bv, bv, bv};

    #pragma unroll
    for (int k0 = 0; k0 < 4; k0++) {
        short8 af[4];
        #pragma unroll
        for (int mt = 0; mt < 4; mt++)
            af[mt] = *(const short8*)(A_s + ((mt * 4 + k0) * 64 + lane) * 8);
        #pragma unroll
        for (int mt = 0; mt < 4; mt++)
            acc[mt] = __builtin_amdgcn_mfma_f32_16x16x32_bf16(af[mt], bw[k0], acc[mt], 0, 0, 0);
    }

    const int col = (wv << 4) + ln16;                 // 0..63
    #pragma unroll
    for (int mt = 0; mt < 4; mt++)
        #pragma unroll
        for (int r = 0; r < 4; r++) {
            int row = mt * 16 + q * 4 + r;            // 0..63
            float v = acc[mt][r];
            out[(size_t)(node0 + row) * FINAL + col] = v;
            XT[(size_t)(bloc * 64 + col) * 256 + (node0 & 255) + row] = to_bf16(v);
        }
}

// ---------- node1 (MFMA): out[:, :, 64:128] = DA @ nff per batch ----------
__global__ __launch_bounds__(256) void k_node1_mfma(
    const __hip_bfloat16* __restrict__ DAf,   // A-fragment order [16][8][64][8]
    const __hip_bfloat16* __restrict__ XT,    // [B][64 f][256 j] bf16
    float* __restrict__ out)
{
    __shared__ __align__(16) __hip_bfloat16 B_s[32 * 512];  // 32 KB
    const int blk = blockIdx.x;
    const int b = blk >> 2, i0 = (blk & 3) * 64;
    const int t = threadIdx.x;
    const int wv = t >> 6, lane = t & 63;
    const int q = lane >> 4, ln16 = lane & 15;

    const __hip_bfloat16* xrow = XT + (size_t)(b * 64 + (wv << 4) + ln16) * 256;
    #pragma unroll
    for (int k0 = 0; k0 < 8; k0++)
        *(uint4*)(B_s + ((wv * 8 + k0) * 64 + lane) * 8) =
            *(const uint4*)(xrow + k0 * 32 + q * 8);
    __syncthreads();

    f32x4 acc[4];
    #pragma unroll
    for (int mt = 0; mt < 4; mt++) acc[mt] = (f32x4){0.f, 0.f, 0.f, 0.f};

    #pragma unroll
    for (int k0 = 0; k0 < 8; k0++) {
        short8 bf = *(const short8*)(B_s + ((wv * 8 + k0) * 64 + lane) * 8);
        short8 af[4];
        #pragma unroll
        for (int mt = 0; mt < 4; mt++)
            af[mt] = *(const short8*)(DAf + (size_t)(((i0 >> 4) + mt) * 8 + k0) * 512 + (lane << 3));
        #pragma unroll
        for (int mt = 0; mt < 4; mt++)
            acc[mt] = __builtin_amdgcn_mfma_f32_16x16x32_bf16(af[mt], bf, acc[mt], 0, 0, 0);
    }

    #pragma unroll
    for (int mt = 0; mt < 4; mt++)
        #pragma unroll
        for (int r = 0; r < 4; r++) {
            int i = i0 + mt * 16 + q * 4 + r;
            out[(size_t)((b << 8) + i) * FINAL + 64 + (wv << 4) + ln16] = acc[mt][r];
        }
}

extern "C" void kernel_launch(void* const* d_in, const int* in_sizes, int n_in,
                              void* d_out, int out_size, void* d_ws, size_t ws_size,
                              hipStream_t stream)
{
    const float* node_fea = (const float*)d_in[0];
    const float* edge_fea = (const float*)d_in[1];
    const int*   eidx     = (const int*)  d_in[2];
    const float* dis      = (const float*)d_in[3];
    const float* Wn = (const float*)d_in[4];
    const float* bn = (const float*)d_in[5];
    const float* We = (const float*)d_in[6];
    const float* be = (const float*)d_in[7];
    const float* W1 = (const float*)d_in[8];
    const float* b1 = (const float*)d_in[9];
    const float* a1 = (const float*)d_in[10];
    const float* W2 = (const float*)d_in[11];
    const float* b2 = (const float*)d_in[12];
    const float* a2 = (const float*)d_in[13];
    const float* W3 = (const float*)d_in[14];
    const float* b3 = (const float*)d_in[15];
    const float* a3 = (const float*)d_in[16];
    const float* Wf = (const float*)d_in[17];
    const float* bf = (const float*)d_in[18];
    const float* DAw = (const float*)d_in[19];
    const float* DAb = (const float*)d_in[20];
    float* out = (float*)d_out;

    // workspace layout (bytes, 256-aligned blocks)
    char* base = (char*)d_ws;
    size_t off = 0;
    auto alloc = [&](size_t bytes) { char* p = base + off; off = (off + bytes + 255) & ~(size_t)255; return p; };
    __hip_bfloat16* nfA = (__hip_bfloat16*)alloc((size_t)Bb * Nn * NF * 2);
    __hip_bfloat16* nfB = (__hip_bfloat16*)alloc((size_t)Bb * Nn * NF * 2);
    __hip_bfloat16* W1b = (__hip_bfloat16*)alloc((size_t)ODIM * KDIM * 2);
    __hip_bfloat16* W2b = (__hip_bfloat16*)alloc((size_t)ODIM * KDIM * 2);
    __hip_bfloat16* W3b = (__hip_bfloat16*)alloc((size_t)ODIM * KDIM * 2);
    float* WeT = (float*)alloc((size_t)OEF * EF * 4);                               // fallback conv path
    __hip_bfloat16* DAf = (__hip_bfloat16*)alloc((size_t)Nn * Nn * 2);              // DA, A-frag order
    __hip_bfloat16* Wnb = (__hip_bfloat16*)alloc((size_t)(NF / 16) * 3 * 512 * 2);  // node embed B, K0=3
    __hip_bfloat16* Web = (__hip_bfloat16*)alloc((size_t)(EF / 16) * 2 * 512 * 2);  // edge embed B, K0=2
    __hip_bfloat16* Wfb = (__hip_bfloat16*)alloc((size_t)(64 / 16) * 4 * 512 * 2);  // final B, K0=4
    __hip_bfloat16* XT  = (__hip_bfloat16*)alloc((size_t)Bb * 64 * Nn * 2);         // nff^T per batch
    __hip_bfloat16* efb = (__hip_bfloat16*)alloc((size_t)Bb * Nn * Mm * EF * 2);    // 33.5 MB
    const bool precomp = (ws_size >= off);

    // prep
    hipLaunchKernelGGL(k_transpose, dim3((EF * OEF + 255) / 256), dim3(256), 0, stream, We, WeT, EF, OEF);
    hipLaunchKernelGGL(k_wswz, dim3((ODIM * KDIM + 255) / 256), dim3(256), 0, stream, W1, W1b);
    hipLaunchKernelGGL(k_wswz, dim3((ODIM * KDIM + 255) / 256), dim3(256), 0, stream, W2, W2b);
    hipLaunchKernelGGL(k_wswz, dim3((ODIM * KDIM + 255) / 256), dim3(256), 0, stream, W3, W3b);
    hipLaunchKernelGGL(k_wswz_pad, dim3(((NF / 16) * 3 * 512 + 255) / 256), dim3(256), 0, stream, Wn, Wnb, NF, ONF, 3);
    hipLaunchKernelGGL(k_wswz_pad, dim3(((EF / 16) * 2 * 512 + 255) / 256), dim3(256), 0, stream, We, Web, EF, OEF, 2);
    hipLaunchKernelGGL(k_wswz_pad, dim3(((64 / 16) * 4 * 512 + 255) / 256), dim3(256), 0, stream, Wf, Wfb, 64, NF, 4);
    hipLaunchKernelGGL(k_da, dim3((Nn * Nn + 255) / 256), dim3(256), 0, stream, dis, DAw, DAb, DAf);

    // embeds (MFMA)
    if (precomp)
        hipLaunchKernelGGL((k_emb<OEF, 2, EF>), dim3(Bb * Nn * Mm / 64), dim3(256), 0, stream,
                           edge_fea, Web, be, efb);
    hipLaunchKernelGGL((k_emb<ONF, 3, NF>), dim3(Bb * Nn / 64), dim3(256), 0, stream,
                       node_fea, Wnb, bn, nfA);

    if (precomp) {
        hipLaunchKernelGGL((k_conv_mfma<true>), dim3(Bb * Nn / 4), dim3(256), 0, stream,
                           nfA, edge_fea, efb, eidx, WeT, be, W1b, b1, a1, nfB);
        hipLaunchKernelGGL((k_conv_mfma<true>), dim3(Bb * Nn / 4), dim3(256), 0, stream,
                           nfB, edge_fea, efb, eidx, WeT, be, W2b, b2, a2, nfA);
        hipLaunchKernelGGL((k_conv_mfma<true>), dim3(Bb * Nn / 4), dim3(256), 0, stream,
                           nfA, edge_fea, efb, eidx, WeT, be, W3b, b3, a3, nfB);
    } else {
        hipLaunchKernelGGL((k_conv_mfma<false>), dim3(Bb * Nn / 4), dim3(256), 0, stream,
                           nfA, edge_fea, efb, eidx, WeT, be, W1b, b1, a1, nfB);
        hipLaunchKernelGGL((k_conv_mfma<false>), dim3(Bb * Nn / 4), dim3(256), 0, stream,
                           nfB, edge_fea, efb, eidx, WeT, be, W2b, b2, a2, nfA);
        hipLaunchKernelGGL((k_conv_mfma<false>), dim3(Bb * Nn / 4), dim3(256), 0, stream,
                           nfA, edge_fea, efb, eidx, WeT, be, W3b, b3, a3, nfB);
    }

    hipLaunchKernelGGL(k_final_mfma, dim3(Bb * Nn / 64), dim3(256), 0, stream, nfB, Wfb, bf, out, XT);
    hipLaunchKernelGGL(k_node1_mfma, dim3(Bb * 4), dim3(256), 0, stream, DAf, XT, out);
}